// Round 4
// baseline (192.564 us; speedup 1.0000x reference)
//
#include <hip/hip_runtime.h>

typedef __attribute__((ext_vector_type(8))) short short8;
typedef __attribute__((ext_vector_type(8))) unsigned short ushort8v;
typedef __attribute__((ext_vector_type(4))) float f32x4;

#define N_NODES 4096
#define N_FEAT  256

__device__ __forceinline__ unsigned short f2bf(float f) {
  union { float f; unsigned u; } a; a.f = f;
  unsigned r = a.u + 0x7FFFu + ((a.u >> 16) & 1u);  // round-to-nearest-even
  return (unsigned short)(r >> 16);
}

__device__ __forceinline__ float bf2f(unsigned short u) {
  union { unsigned u; float f; } a; a.u = ((unsigned)u) << 16;
  return a.f;
}

__device__ __forceinline__ void gload_lds16(const void* g, void* l) {
  __builtin_amdgcn_global_load_lds(
      (const __attribute__((address_space(1))) void*)g,
      (__attribute__((address_space(3))) void*)l, 16, 0, 0);
}

// ------------------------------------------- V -> Vbf (bf16) + Vt (bf16, transposed)
__global__ __launch_bounds__(256) void prep_v_k(const float* __restrict__ V,
                                                unsigned short* __restrict__ Vbf,
                                                unsigned short* __restrict__ Vt) {
  __shared__ unsigned short tile[64][72];
  const int t = threadIdx.x;
  const int r = t >> 2, q = t & 3;
  const int gr = blockIdx.y * 64 + r;
  const int gc0 = blockIdx.x * 64;
#pragma unroll
  for (int i = 0; i < 4; ++i) {
    int c = q * 4 + i * 16;
    float4 v = *(const float4*)&V[(size_t)gr * N_NODES + gc0 + c];
    ushort4 u; u.x = f2bf(v.x); u.y = f2bf(v.y); u.z = f2bf(v.z); u.w = f2bf(v.w);
    *(ushort4*)&Vbf[(size_t)gr * N_NODES + gc0 + c] = u;
    tile[c + 0][r] = u.x; tile[c + 1][r] = u.y; tile[c + 2][r] = u.z; tile[c + 3][r] = u.w;
  }
  __syncthreads();
  const int r2 = t >> 2;  // transposed row = V column
#pragma unroll
  for (int j = 0; j < 2; ++j) {
    int ms = q * 8 + j * 32;
    ushort8v u = *(const ushort8v*)&tile[r2][ms];
    *(ushort8v*)&Vt[(size_t)(gc0 + r2) * N_NODES + blockIdx.y * 64 + ms] = u;
  }
}

// ------------------------------ x,y -> S2T[512][4096] bf16: S2T[2f+s][j] = (s?y:x)[j][f]
__global__ __launch_bounds__(256) void prep_xy_k(const float* __restrict__ x,
                                                 const float* __restrict__ y,
                                                 unsigned short* __restrict__ S2T) {
  __shared__ unsigned short tx[64][72];
  __shared__ unsigned short ty[64][72];
  const int t = threadIdx.x;
  const int r = t >> 2, q = t & 3;
  const int gj = blockIdx.y * 64 + r;
  const int gf0 = blockIdx.x * 64;
#pragma unroll
  for (int i = 0; i < 4; ++i) {
    int c = q * 4 + i * 16;
    float4 vx = *(const float4*)&x[(size_t)gj * N_FEAT + gf0 + c];
    float4 vy = *(const float4*)&y[(size_t)gj * N_FEAT + gf0 + c];
    tx[c + 0][r] = f2bf(vx.x); tx[c + 1][r] = f2bf(vx.y);
    tx[c + 2][r] = f2bf(vx.z); tx[c + 3][r] = f2bf(vx.w);
    ty[c + 0][r] = f2bf(vy.x); ty[c + 1][r] = f2bf(vy.y);
    ty[c + 2][r] = f2bf(vy.z); ty[c + 3][r] = f2bf(vy.w);
  }
  __syncthreads();
  const int f2 = t >> 2;
#pragma unroll
  for (int j = 0; j < 2; ++j) {
    int js = q * 8 + j * 32;
    ushort8v ux = *(const ushort8v*)&tx[f2][js];
    ushort8v uy = *(const ushort8v*)&ty[f2][js];
    *(ushort8v*)&S2T[(size_t)(2 * (gf0 + f2) + 0) * N_NODES + blockIdx.y * 64 + js] = ux;
    *(ushort8v*)&S2T[(size_t)(2 * (gf0 + f2) + 1) * N_NODES + blockIdx.y * 64 + js] = uy;
  }
}

// --------------------------------------------------------------- split-K GEMM
// BM=128, BN=64, BK=64, 256 threads (4 waves 2x2), wave tile 64x32.
// XCD-bijective remap (xcd = L%8 owns contiguous (mtile,z) groups, ntile-sharers
// co-resident). LDS double-buffered (T3 minimum 2-phase): stage tile t+1 into
// buf^1 BEFORE computing tile t; one barrier per K-step. XOR slot-swizzle via
// pre-swizzled global source (LDS dest stays linear for global_load_lds).
// Partials stored as bf16.
template <int NTB>
__global__ __launch_bounds__(256, 3) void gemm_swz(const unsigned short* __restrict__ A,
                                                   const unsigned short* __restrict__ B,
                                                   unsigned short* __restrict__ part,
                                                   int K, int Kc, int Nn, size_t MN) {
  __shared__ unsigned short As[2][128 * 64];
  __shared__ unsigned short Bs[2][64 * 64];
  const int t = threadIdx.x;
  const int lane = t & 63, w = t >> 6;

  const unsigned L = blockIdx.x;
  const unsigned cx = L & 7u, j = L >> 3;
  const unsigned ntile = j & ((1u << NTB) - 1u);
  const unsigned group = cx * (128u >> NTB) + (j >> NTB);
  const unsigned mtile = group & 31u;
  const unsigned zz = group >> 5u;

  const int wr = (w >> 1) * 64;
  const int wc = (w & 1) * 32;
  const int l15 = lane & 15;
  const int lhi = lane >> 4;

  const size_t kbase = (size_t)zz * Kc;
  // pre-swizzled per-lane source offset (bytes): row lane>>3, k-slot (lane&7)^(lane>>3)
  const size_t srcoff = (size_t)(lane >> 3) * K * 2 + (size_t)(((lane & 7) ^ (lane >> 3)) << 4);

  const char* Ag = (const char*)(A + (size_t)mtile * 128 * K + kbase);
  const char* Bg = (const char*)(B + (size_t)ntile * 64 * K + kbase);

  f32x4 acc[4][2];
#pragma unroll
  for (int mi = 0; mi < 4; ++mi)
#pragma unroll
    for (int ni = 0; ni < 2; ++ni) acc[mi][ni] = (f32x4){0.f, 0.f, 0.f, 0.f};

  auto STAGE = [&](int kt, int cur) {
    const size_t ko = (size_t)kt * 128;  // BK=64 bf16 = 128 B
#pragma unroll
    for (int q = 0; q < 4; ++q)
      gload_lds16(Ag + (size_t)(w * 4 + q) * 8 * K * 2 + srcoff + ko,
                  &As[cur][(w * 4 + q) * 512]);
#pragma unroll
    for (int q = 0; q < 2; ++q)
      gload_lds16(Bg + (size_t)(w * 2 + q) * 8 * K * 2 + srcoff + ko,
                  &Bs[cur][(w * 2 + q) * 512]);
  };

  auto COMPUTE = [&](int cur) {
    short8 a[4][2], b[2][2];
#pragma unroll
    for (int mi = 0; mi < 4; ++mi) {
      const int ar = wr + mi * 16 + l15;
#pragma unroll
      for (int ks = 0; ks < 2; ++ks)
        a[mi][ks] = *(const short8*)((const char*)&As[cur][0] + (size_t)ar * 128 +
                                     ((((ks << 2) | lhi) ^ (ar & 7)) << 4));
    }
#pragma unroll
    for (int ni = 0; ni < 2; ++ni) {
      const int br = wc + ni * 16 + l15;
#pragma unroll
      for (int ks = 0; ks < 2; ++ks)
        b[ni][ks] = *(const short8*)((const char*)&Bs[cur][0] + (size_t)br * 128 +
                                     ((((ks << 2) | lhi) ^ (br & 7)) << 4));
    }
#pragma unroll
    for (int ks = 0; ks < 2; ++ks)
#pragma unroll
      for (int mi = 0; mi < 4; ++mi)
#pragma unroll
        for (int ni = 0; ni < 2; ++ni)
          acc[mi][ni] = __builtin_amdgcn_mfma_f32_16x16x32_bf16(a[mi][ks], b[ni][ks],
                                                                acc[mi][ni], 0, 0, 0);
  };

  const int nkt = Kc >> 6;
  STAGE(0, 0);
  __syncthreads();
  int cur = 0;
  for (int kt = 0; kt < nkt - 1; ++kt) {
    STAGE(kt + 1, cur ^ 1);   // issue next-tile loads first; they drain at the barrier
    COMPUTE(cur);
    __syncthreads();
    cur ^= 1;
  }
  COMPUTE(cur);

  unsigned short* po = part + (size_t)zz * MN;
  const int m0 = mtile * 128 + wr + lhi * 4;
  const int n0 = ntile * 64 + wc + l15;
#pragma unroll
  for (int mi = 0; mi < 4; ++mi)
#pragma unroll
    for (int ni = 0; ni < 2; ++ni)
#pragma unroll
      for (int r = 0; r < 4; ++r)
        po[(size_t)(m0 + mi * 16 + r) * Nn + n0 + ni * 16] = f2bf(acc[mi][ni][r]);
}

// --------------- reduce1: Zt[f][m] = c[m]*sum_ks part[ks][m][2f] + p2[m]*sum_ks part[ks][m][2f+1]
// spectrum (cos/sinc) computed inline; LDS transpose; 16B coalesced stores.
__global__ __launch_bounds__(256) void reduce1_k(const unsigned short* __restrict__ part,
                                                 const float* __restrict__ lam,
                                                 const float* __restrict__ tp,
                                                 unsigned short* __restrict__ Zt) {
  __shared__ unsigned short zt[64][72];
  const int t = threadIdx.x;
  const int r = t >> 2, q = t & 3;
  const int m = blockIdx.y * 64 + r;
  const int n0 = blockIdx.x * 128;
  const float tv = tp[0];
  const float s = sqrtf(fmaxf(lam[m], 0.f));
  const float cv = cosf(tv * s);
  const float pv = (s < 1e-5f) ? tv : (sinf(tv * s) / s);
  float acc[16];
#pragma unroll
  for (int i = 0; i < 16; ++i) acc[i] = 0.f;
  for (int ks = 0; ks < 4; ++ks) {
    const unsigned short* p = part + ((size_t)ks * N_NODES + m) * 512 + n0;
#pragma unroll
    for (int i = 0; i < 8; ++i) {
      ushort4 u = *(const ushort4*)&p[q * 4 + i * 16];  // (x_f, y_f, x_{f+1}, y_{f+1})
      acc[2 * i + 0] += cv * bf2f(u.x) + pv * bf2f(u.y);
      acc[2 * i + 1] += cv * bf2f(u.z) + pv * bf2f(u.w);
    }
  }
#pragma unroll
  for (int i = 0; i < 8; ++i) {
    int f = q * 2 + i * 8;
    zt[f + 0][r] = f2bf(acc[2 * i + 0]);
    zt[f + 1][r] = f2bf(acc[2 * i + 1]);
  }
  __syncthreads();
  const int f2 = t >> 2;
  const int gf = blockIdx.x * 64 + f2;
#pragma unroll
  for (int w = 0; w < 2; ++w) {
    int js = q * 8 + w * 32;
    ushort8v u = *(const ushort8v*)&zt[f2][js];
    *(ushort8v*)&Zt[(size_t)gf * N_NODES + blockIdx.y * 64 + js] = u;
  }
}

// --------------- reduce2: out[e] = sum_{ks<8} part[ks][e]  (bf16 partials -> f32)
__global__ __launch_bounds__(256) void reduce2_k(const unsigned short* __restrict__ part,
                                                 float* __restrict__ out) {
  const size_t e = ((size_t)blockIdx.x * 256 + threadIdx.x) * 4;
  float4 s = {0.f, 0.f, 0.f, 0.f};
#pragma unroll
  for (int ks = 0; ks < 8; ++ks) {
    ushort4 u = *(const ushort4*)&part[(size_t)ks * N_NODES * N_FEAT + e];
    s.x += bf2f(u.x); s.y += bf2f(u.y); s.z += bf2f(u.z); s.w += bf2f(u.w);
  }
  *(float4*)&out[e] = s;
}

extern "C" void kernel_launch(void* const* d_in, const int* in_sizes, int n_in,
                              void* d_out, int out_size, void* d_ws, size_t ws_size,
                              hipStream_t stream) {
  const float* x   = (const float*)d_in[0];
  const float* y   = (const float*)d_in[1];
  const float* tp  = (const float*)d_in[2];
  const float* lam = (const float*)d_in[3];
  const float* V   = (const float*)d_in[4];

  char* w = (char*)d_ws;
  unsigned short* Vbf  = (unsigned short*)w; w += (size_t)N_NODES * N_NODES * 2;
  unsigned short* Vtbf = (unsigned short*)w; w += (size_t)N_NODES * N_NODES * 2;
  unsigned short* S2T  = (unsigned short*)w; w += (size_t)512 * N_NODES * 2;
  unsigned short* Zt   = (unsigned short*)w; w += (size_t)N_FEAT * N_NODES * 2;
  unsigned short* partb = (unsigned short*)w; w += (size_t)4 * N_NODES * 512 * 2;  // 16MB bf16

  prep_v_k<<<dim3(N_NODES / 64, N_NODES / 64), 256, 0, stream>>>(V, Vbf, Vtbf);
  prep_xy_k<<<dim3(N_FEAT / 64, N_NODES / 64), 256, 0, stream>>>(x, y, S2T);
  // GEMM1: part[z][i][s] = Vt[i, z-chunk] . S2T[s, z-chunk]   (z=4, Kc=1024, NTB=3)
  gemm_swz<3><<<1024, 256, 0, stream>>>(Vtbf, S2T, partb, N_NODES, 1024, 512,
                                        (size_t)N_NODES * 512);
  reduce1_k<<<dim3(512 / 128, N_NODES / 64), 256, 0, stream>>>(partb, lam, tp, Zt);
  // GEMM2: part[z][j][f] = Vbf[j, z-chunk] . Zt[f, z-chunk]   (z=8, Kc=512, NTB=2)
  gemm_swz<2><<<1024, 256, 0, stream>>>(Vbf, Zt, partb, N_NODES, 512, N_FEAT,
                                        (size_t)N_NODES * N_FEAT);
  reduce2_k<<<(N_NODES * N_FEAT) / 1024, 256, 0, stream>>>(partb, (float*)d_out);
}

// Round 5
// 174.198 us; speedup vs baseline: 1.1054x; 1.1054x over previous
//
#include <hip/hip_runtime.h>

typedef __attribute__((ext_vector_type(8))) short short8;
typedef __attribute__((ext_vector_type(8))) unsigned short ushort8v;
typedef __attribute__((ext_vector_type(4))) float f32x4;

#define N_NODES 4096
#define N_FEAT  256

__device__ __forceinline__ unsigned short f2bf(float f) {
  union { float f; unsigned u; } a; a.f = f;
  unsigned r = a.u + 0x7FFFu + ((a.u >> 16) & 1u);  // round-to-nearest-even
  return (unsigned short)(r >> 16);
}

__device__ __forceinline__ float bf2f(unsigned short u) {
  union { unsigned u; float f; } a; a.u = ((unsigned)u) << 16;
  return a.f;
}

__device__ __forceinline__ void gload_lds16(const void* g, void* l) {
  __builtin_amdgcn_global_load_lds(
      (const __attribute__((address_space(1))) void*)g,
      (__attribute__((address_space(3))) void*)l, 16, 0, 0);
}

// ------------------------------------------- V -> Vbf (bf16) + Vt (bf16, transposed)
__global__ __launch_bounds__(256) void prep_v_k(const float* __restrict__ V,
                                                unsigned short* __restrict__ Vbf,
                                                unsigned short* __restrict__ Vt) {
  __shared__ unsigned short tile[64][72];
  const int t = threadIdx.x;
  const int r = t >> 2, q = t & 3;
  const int gr = blockIdx.y * 64 + r;
  const int gc0 = blockIdx.x * 64;
#pragma unroll
  for (int i = 0; i < 4; ++i) {
    int c = q * 4 + i * 16;
    float4 v = *(const float4*)&V[(size_t)gr * N_NODES + gc0 + c];
    ushort4 u; u.x = f2bf(v.x); u.y = f2bf(v.y); u.z = f2bf(v.z); u.w = f2bf(v.w);
    *(ushort4*)&Vbf[(size_t)gr * N_NODES + gc0 + c] = u;
    tile[c + 0][r] = u.x; tile[c + 1][r] = u.y; tile[c + 2][r] = u.z; tile[c + 3][r] = u.w;
  }
  __syncthreads();
  const int r2 = t >> 2;  // transposed row = V column
#pragma unroll
  for (int j = 0; j < 2; ++j) {
    int ms = q * 8 + j * 32;
    ushort8v u = *(const ushort8v*)&tile[r2][ms];
    *(ushort8v*)&Vt[(size_t)(gc0 + r2) * N_NODES + blockIdx.y * 64 + ms] = u;
  }
}

// ------------------------------ x,y -> S2T[512][4096] bf16: S2T[2f+s][j] = (s?y:x)[j][f]
__global__ __launch_bounds__(256) void prep_xy_k(const float* __restrict__ x,
                                                 const float* __restrict__ y,
                                                 unsigned short* __restrict__ S2T) {
  __shared__ unsigned short tx[64][72];
  __shared__ unsigned short ty[64][72];
  const int t = threadIdx.x;
  const int r = t >> 2, q = t & 3;
  const int gj = blockIdx.y * 64 + r;
  const int gf0 = blockIdx.x * 64;
#pragma unroll
  for (int i = 0; i < 4; ++i) {
    int c = q * 4 + i * 16;
    float4 vx = *(const float4*)&x[(size_t)gj * N_FEAT + gf0 + c];
    float4 vy = *(const float4*)&y[(size_t)gj * N_FEAT + gf0 + c];
    tx[c + 0][r] = f2bf(vx.x); tx[c + 1][r] = f2bf(vx.y);
    tx[c + 2][r] = f2bf(vx.z); tx[c + 3][r] = f2bf(vx.w);
    ty[c + 0][r] = f2bf(vy.x); ty[c + 1][r] = f2bf(vy.y);
    ty[c + 2][r] = f2bf(vy.z); ty[c + 3][r] = f2bf(vy.w);
  }
  __syncthreads();
  const int f2 = t >> 2;
#pragma unroll
  for (int j = 0; j < 2; ++j) {
    int js = q * 8 + j * 32;
    ushort8v ux = *(const ushort8v*)&tx[f2][js];
    ushort8v uy = *(const ushort8v*)&ty[f2][js];
    *(ushort8v*)&S2T[(size_t)(2 * (gf0 + f2) + 0) * N_NODES + blockIdx.y * 64 + js] = ux;
    *(ushort8v*)&S2T[(size_t)(2 * (gf0 + f2) + 1) * N_NODES + blockIdx.y * 64 + js] = uy;
  }
}

// --------------------------------------------------------------- split-K GEMM
// BM=128, BN=128, BK=64, 256 threads (4 waves 2x2), wave tile 64x64 (acc[4][4]).
// Single-buffered LDS (32 KB): stage; barrier; compute; barrier. XOR slot-swizzle
// via pre-swizzled global source (LDS dest linear for global_load_lds).
// XCD-bijective remap: L%8 = xcd; group = cx*GPX + (j>>NTB); mtile=group&31,
// zz=group>>5 -> each XCD reads one (or two) contiguous K-chunks that fit its L2,
// and all 2^NTB ntile-sharers of an A-panel are co-resident on one XCD.
// Partials stored bf16.
template <int NTB>
__global__ __launch_bounds__(256, 3) void gemm_swz(const unsigned short* __restrict__ A,
                                                   const unsigned short* __restrict__ B,
                                                   unsigned short* __restrict__ part,
                                                   int K, int Kc, int Nn, size_t MN) {
  __shared__ unsigned short As[128 * 64];
  __shared__ unsigned short Bs[128 * 64];
  const int t = threadIdx.x;
  const int lane = t & 63, w = t >> 6;

  const unsigned L = blockIdx.x;
  const unsigned cx = L & 7u, j = L >> 3u;
  const unsigned ntile = j & ((1u << NTB) - 1u);
  const unsigned GPX = (gridDim.x >> 3) >> NTB;
  const unsigned group = cx * GPX + (j >> NTB);
  const unsigned mtile = group & 31u;
  const unsigned zz = group >> 5u;

  const int wr = (w >> 1) * 64;
  const int wc = (w & 1) * 64;
  const int l15 = lane & 15;
  const int lhi = lane >> 4;

  const size_t kbase = (size_t)zz * Kc;
  // pre-swizzled per-lane source offset (bytes): row lane>>3, k-slot (lane&7)^(lane>>3)
  const size_t srcoff = (size_t)(lane >> 3) * K * 2 + (size_t)(((lane & 7) ^ (lane >> 3)) << 4);

  const char* Ag = (const char*)(A + (size_t)mtile * 128 * K + kbase);
  const char* Bg = (const char*)(B + (size_t)ntile * 128 * K + kbase);

  f32x4 acc[4][4];
#pragma unroll
  for (int mi = 0; mi < 4; ++mi)
#pragma unroll
    for (int ni = 0; ni < 4; ++ni) acc[mi][ni] = (f32x4){0.f, 0.f, 0.f, 0.f};

  const int nkt = Kc >> 6;
  for (int kt = 0; kt < nkt; ++kt) {
    const size_t ko = (size_t)kt * 128;  // BK=64 bf16 = 128 B
#pragma unroll
    for (int q = 0; q < 4; ++q)
      gload_lds16(Ag + (size_t)(w * 4 + q) * 8 * K * 2 + srcoff + ko, &As[(w * 4 + q) * 512]);
#pragma unroll
    for (int q = 0; q < 4; ++q)
      gload_lds16(Bg + (size_t)(w * 4 + q) * 8 * K * 2 + srcoff + ko, &Bs[(w * 4 + q) * 512]);
    __syncthreads();
#pragma unroll
    for (int ks = 0; ks < 2; ++ks) {
      short8 a[4], b[4];
#pragma unroll
      for (int mi = 0; mi < 4; ++mi) {
        const int ar = wr + mi * 16 + l15;
        a[mi] = *(const short8*)((const char*)As + (size_t)ar * 128 +
                                 ((((ks << 2) | lhi) ^ (ar & 7)) << 4));
      }
#pragma unroll
      for (int ni = 0; ni < 4; ++ni) {
        const int br = wc + ni * 16 + l15;
        b[ni] = *(const short8*)((const char*)Bs + (size_t)br * 128 +
                                 ((((ks << 2) | lhi) ^ (br & 7)) << 4));
      }
#pragma unroll
      for (int mi = 0; mi < 4; ++mi)
#pragma unroll
        for (int ni = 0; ni < 4; ++ni)
          acc[mi][ni] = __builtin_amdgcn_mfma_f32_16x16x32_bf16(a[mi], b[ni],
                                                                acc[mi][ni], 0, 0, 0);
    }
    __syncthreads();
  }

  unsigned short* po = part + (size_t)zz * MN;
  const int m0 = mtile * 128 + wr + lhi * 4;
  const int n0 = ntile * 128 + wc + l15;
#pragma unroll
  for (int mi = 0; mi < 4; ++mi)
#pragma unroll
    for (int ni = 0; ni < 4; ++ni)
#pragma unroll
      for (int r = 0; r < 4; ++r)
        po[(size_t)(m0 + mi * 16 + r) * Nn + n0 + ni * 16] = f2bf(acc[mi][ni][r]);
}

// --------------- reduce1: Zt[f][m] = c[m]*sum_ks part[ks][m][2f] + p2[m]*sum_ks part[ks][m][2f+1]
// spectrum (cos/sinc) computed inline; LDS transpose; 16B coalesced stores.
__global__ __launch_bounds__(256) void reduce1_k(const unsigned short* __restrict__ part,
                                                 const float* __restrict__ lam,
                                                 const float* __restrict__ tp,
                                                 unsigned short* __restrict__ Zt) {
  __shared__ unsigned short zt[64][72];
  const int t = threadIdx.x;
  const int r = t >> 2, q = t & 3;
  const int m = blockIdx.y * 64 + r;
  const int n0 = blockIdx.x * 128;
  const float tv = tp[0];
  const float s = sqrtf(fmaxf(lam[m], 0.f));
  const float cv = cosf(tv * s);
  const float pv = (s < 1e-5f) ? tv : (sinf(tv * s) / s);
  float acc[16];
#pragma unroll
  for (int i = 0; i < 16; ++i) acc[i] = 0.f;
  for (int ks = 0; ks < 8; ++ks) {
    const unsigned short* p = part + ((size_t)ks * N_NODES + m) * 512 + n0;
#pragma unroll
    for (int i = 0; i < 8; ++i) {
      ushort4 u = *(const ushort4*)&p[q * 4 + i * 16];  // (x_f, y_f, x_{f+1}, y_{f+1})
      acc[2 * i + 0] += cv * bf2f(u.x) + pv * bf2f(u.y);
      acc[2 * i + 1] += cv * bf2f(u.z) + pv * bf2f(u.w);
    }
  }
#pragma unroll
  for (int i = 0; i < 8; ++i) {
    int f = q * 2 + i * 8;
    zt[f + 0][r] = f2bf(acc[2 * i + 0]);
    zt[f + 1][r] = f2bf(acc[2 * i + 1]);
  }
  __syncthreads();
  const int f2 = t >> 2;
  const int gf = blockIdx.x * 64 + f2;
#pragma unroll
  for (int w = 0; w < 2; ++w) {
    int js = q * 8 + w * 32;
    ushort8v u = *(const ushort8v*)&zt[f2][js];
    *(ushort8v*)&Zt[(size_t)gf * N_NODES + blockIdx.y * 64 + js] = u;
  }
}

// --------------- reduce2: out[e] = sum_{ks<16} part[ks][e]  (bf16 partials -> f32)
__global__ __launch_bounds__(256) void reduce2_k(const unsigned short* __restrict__ part,
                                                 float* __restrict__ out) {
  const size_t e = ((size_t)blockIdx.x * 256 + threadIdx.x) * 4;
  float4 s = {0.f, 0.f, 0.f, 0.f};
#pragma unroll
  for (int ks = 0; ks < 16; ++ks) {
    ushort4 u = *(const ushort4*)&part[(size_t)ks * N_NODES * N_FEAT + e];
    s.x += bf2f(u.x); s.y += bf2f(u.y); s.z += bf2f(u.z); s.w += bf2f(u.w);
  }
  *(float4*)&out[e] = s;
}

extern "C" void kernel_launch(void* const* d_in, const int* in_sizes, int n_in,
                              void* d_out, int out_size, void* d_ws, size_t ws_size,
                              hipStream_t stream) {
  const float* x   = (const float*)d_in[0];
  const float* y   = (const float*)d_in[1];
  const float* tp  = (const float*)d_in[2];
  const float* lam = (const float*)d_in[3];
  const float* V   = (const float*)d_in[4];

  char* w = (char*)d_ws;
  unsigned short* Vbf  = (unsigned short*)w; w += (size_t)N_NODES * N_NODES * 2;
  unsigned short* Vtbf = (unsigned short*)w; w += (size_t)N_NODES * N_NODES * 2;
  unsigned short* S2T  = (unsigned short*)w; w += (size_t)512 * N_NODES * 2;
  unsigned short* Zt   = (unsigned short*)w; w += (size_t)N_FEAT * N_NODES * 2;
  unsigned short* partb = (unsigned short*)w; w += (size_t)8 * N_NODES * 512 * 2;  // 33.6MB bf16

  prep_v_k<<<dim3(N_NODES / 64, N_NODES / 64), 256, 0, stream>>>(V, Vbf, Vtbf);
  prep_xy_k<<<dim3(N_FEAT / 64, N_NODES / 64), 256, 0, stream>>>(x, y, S2T);
  // GEMM1: part[z][i][s] = Vt[i, z-chunk] . S2T[s, z-chunk]
  // z=8, Kc=512, BN=128 (4 ntiles, NTB=2); 1024 blocks; zz == xcd (4MB A-chunk per L2)
  gemm_swz<2><<<1024, 256, 0, stream>>>(Vtbf, S2T, partb, N_NODES, 512, 512,
                                        (size_t)N_NODES * 512);
  reduce1_k<<<dim3(512 / 128, N_NODES / 64), 256, 0, stream>>>(partb, lam, tp, Zt);
  // GEMM2: part[z][j][f] = Vbf[j, z-chunk] . Zt[f, z-chunk]
  // z=16, Kc=256, BN=128 (2 ntiles, NTB=1); 1024 blocks; each XCD covers 2 K-chunks
  gemm_swz<1><<<1024, 256, 0, stream>>>(Vbf, Zt, partb, N_NODES, 256, N_FEAT,
                                        (size_t)N_NODES * N_FEAT);
  reduce2_k<<<(N_NODES * N_FEAT) / 1024, 256, 0, stream>>>(partb, (float*)d_out);
}

// Round 6
// 170.825 us; speedup vs baseline: 1.1273x; 1.0197x over previous
//
#include <hip/hip_runtime.h>

typedef __attribute__((ext_vector_type(8))) short short8;
typedef __attribute__((ext_vector_type(8))) unsigned short ushort8v;
typedef __attribute__((ext_vector_type(4))) float f32x4;

#define N_NODES 4096
#define N_FEAT  256

__device__ __forceinline__ unsigned short f2bf(float f) {
  union { float f; unsigned u; } a; a.f = f;
  unsigned r = a.u + 0x7FFFu + ((a.u >> 16) & 1u);  // round-to-nearest-even
  return (unsigned short)(r >> 16);
}

__device__ __forceinline__ float bf2f(unsigned short u) {
  union { unsigned u; float f; } a; a.u = ((unsigned)u) << 16;
  return a.f;
}

__device__ __forceinline__ void gload_lds16(const void* g, void* l) {
  __builtin_amdgcn_global_load_lds(
      (const __attribute__((address_space(1))) void*)g,
      (__attribute__((address_space(3))) void*)l, 16, 0, 0);
}

// ---------------- fused prep: blocks [0,4096) do V->Vbf+Vt; [4096,4352) do x,y->S2T
__global__ __launch_bounds__(256) void prep_all_k(const float* __restrict__ V,
                                                  const float* __restrict__ x,
                                                  const float* __restrict__ y,
                                                  unsigned short* __restrict__ Vbf,
                                                  unsigned short* __restrict__ Vt,
                                                  unsigned short* __restrict__ S2T) {
  __shared__ unsigned short smem[2][64][72];
  const int t = threadIdx.x;
  const int r = t >> 2, q = t & 3;
  const unsigned b = blockIdx.x;
  if (b < 4096u) {
    // ---- prep_v: 64x64 tile transpose + convert
    const int bx = b & 63, by = b >> 6;
    const int gr = by * 64 + r;
    const int gc0 = bx * 64;
#pragma unroll
    for (int i = 0; i < 4; ++i) {
      int c = q * 4 + i * 16;
      float4 v = *(const float4*)&V[(size_t)gr * N_NODES + gc0 + c];
      ushort4 u; u.x = f2bf(v.x); u.y = f2bf(v.y); u.z = f2bf(v.z); u.w = f2bf(v.w);
      *(ushort4*)&Vbf[(size_t)gr * N_NODES + gc0 + c] = u;
      smem[0][c + 0][r] = u.x; smem[0][c + 1][r] = u.y;
      smem[0][c + 2][r] = u.z; smem[0][c + 3][r] = u.w;
    }
    __syncthreads();
    const int r2 = t >> 2;  // transposed row = V column
#pragma unroll
    for (int j = 0; j < 2; ++j) {
      int ms = q * 8 + j * 32;
      ushort8v u = *(const ushort8v*)&smem[0][r2][ms];
      *(ushort8v*)&Vt[(size_t)(gc0 + r2) * N_NODES + by * 64 + ms] = u;
    }
  } else {
    // ---- prep_xy: S2T[2f+s][j] = (s?y:x)[j][f]
    const unsigned b2 = b - 4096u;
    const int bx = b2 & 3, by = b2 >> 2;
    const int gj = by * 64 + r;
    const int gf0 = bx * 64;
#pragma unroll
    for (int i = 0; i < 4; ++i) {
      int c = q * 4 + i * 16;
      float4 vx = *(const float4*)&x[(size_t)gj * N_FEAT + gf0 + c];
      float4 vy = *(const float4*)&y[(size_t)gj * N_FEAT + gf0 + c];
      smem[0][c + 0][r] = f2bf(vx.x); smem[0][c + 1][r] = f2bf(vx.y);
      smem[0][c + 2][r] = f2bf(vx.z); smem[0][c + 3][r] = f2bf(vx.w);
      smem[1][c + 0][r] = f2bf(vy.x); smem[1][c + 1][r] = f2bf(vy.y);
      smem[1][c + 2][r] = f2bf(vy.z); smem[1][c + 3][r] = f2bf(vy.w);
    }
    __syncthreads();
    const int f2 = t >> 2;
#pragma unroll
    for (int j = 0; j < 2; ++j) {
      int js = q * 8 + j * 32;
      ushort8v ux = *(const ushort8v*)&smem[0][f2][js];
      ushort8v uy = *(const ushort8v*)&smem[1][f2][js];
      *(ushort8v*)&S2T[(size_t)(2 * (gf0 + f2) + 0) * N_NODES + by * 64 + js] = ux;
      *(ushort8v*)&S2T[(size_t)(2 * (gf0 + f2) + 1) * N_NODES + by * 64 + js] = uy;
    }
  }
}

// --------------------------------------------------------------- split-K GEMM
// BM=128, BN=128, BK=64, 256 threads (4 waves 2x2), wave tile 64x64 (acc[4][4]).
// Single-buffered LDS (32 KB); 4 blocks/CU via __launch_bounds__(256,4).
// XOR slot-swizzle via pre-swizzled global source (LDS dest linear).
// XCD-bijective remap: L%8 = xcd owns contiguous (mtile,z) groups; ntile-sharers
// of an A-panel co-resident on one XCD; z-chunk of A fits that XCD's 4MB L2.
// Partials stored bf16.
template <int NTB>
__global__ __launch_bounds__(256, 4) void gemm_swz(const unsigned short* __restrict__ A,
                                                   const unsigned short* __restrict__ B,
                                                   unsigned short* __restrict__ part,
                                                   int K, int Kc, int Nn, size_t MN) {
  __shared__ unsigned short As[128 * 64];
  __shared__ unsigned short Bs[128 * 64];
  const int t = threadIdx.x;
  const int lane = t & 63, w = t >> 6;

  const unsigned L = blockIdx.x;
  const unsigned cx = L & 7u, j = L >> 3u;
  const unsigned ntile = j & ((1u << NTB) - 1u);
  const unsigned GPX = (gridDim.x >> 3) >> NTB;
  const unsigned group = cx * GPX + (j >> NTB);
  const unsigned mtile = group & 31u;
  const unsigned zz = group >> 5u;

  const int wr = (w >> 1) * 64;
  const int wc = (w & 1) * 64;
  const int l15 = lane & 15;
  const int lhi = lane >> 4;

  const size_t kbase = (size_t)zz * Kc;
  // pre-swizzled per-lane source offset (bytes): row lane>>3, k-slot (lane&7)^(lane>>3)
  const size_t srcoff = (size_t)(lane >> 3) * K * 2 + (size_t)(((lane & 7) ^ (lane >> 3)) << 4);

  const char* Ag = (const char*)(A + (size_t)mtile * 128 * K + kbase);
  const char* Bg = (const char*)(B + (size_t)ntile * 128 * K + kbase);

  f32x4 acc[4][4];
#pragma unroll
  for (int mi = 0; mi < 4; ++mi)
#pragma unroll
    for (int ni = 0; ni < 4; ++ni) acc[mi][ni] = (f32x4){0.f, 0.f, 0.f, 0.f};

  const int nkt = Kc >> 6;
  for (int kt = 0; kt < nkt; ++kt) {
    const size_t ko = (size_t)kt * 128;  // BK=64 bf16 = 128 B
#pragma unroll
    for (int q = 0; q < 4; ++q)
      gload_lds16(Ag + (size_t)(w * 4 + q) * 8 * K * 2 + srcoff + ko, &As[(w * 4 + q) * 512]);
#pragma unroll
    for (int q = 0; q < 4; ++q)
      gload_lds16(Bg + (size_t)(w * 4 + q) * 8 * K * 2 + srcoff + ko, &Bs[(w * 4 + q) * 512]);
    __syncthreads();
#pragma unroll
    for (int ks = 0; ks < 2; ++ks) {
      short8 a[4], b[4];
#pragma unroll
      for (int mi = 0; mi < 4; ++mi) {
        const int ar = wr + mi * 16 + l15;
        a[mi] = *(const short8*)((const char*)As + (size_t)ar * 128 +
                                 ((((ks << 2) | lhi) ^ (ar & 7)) << 4));
      }
#pragma unroll
      for (int ni = 0; ni < 4; ++ni) {
        const int br = wc + ni * 16 + l15;
        b[ni] = *(const short8*)((const char*)Bs + (size_t)br * 128 +
                                 ((((ks << 2) | lhi) ^ (br & 7)) << 4));
      }
#pragma unroll
      for (int mi = 0; mi < 4; ++mi)
#pragma unroll
        for (int ni = 0; ni < 4; ++ni)
          acc[mi][ni] = __builtin_amdgcn_mfma_f32_16x16x32_bf16(a[mi], b[ni],
                                                                acc[mi][ni], 0, 0, 0);
    }
    __syncthreads();
  }

  unsigned short* po = part + (size_t)zz * MN;
  const int m0 = mtile * 128 + wr + lhi * 4;
  const int n0 = ntile * 128 + wc + l15;
#pragma unroll
  for (int mi = 0; mi < 4; ++mi)
#pragma unroll
    for (int ni = 0; ni < 4; ++ni)
#pragma unroll
      for (int r = 0; r < 4; ++r)
        po[(size_t)(m0 + mi * 16 + r) * Nn + n0 + ni * 16] = f2bf(acc[mi][ni][r]);
}

// --------------- reduce1: Zt[f][m] = c[m]*sum_ks part[ks][m][2f] + p2[m]*sum_ks part[ks][m][2f+1]
// spectrum (cos/sinc) computed inline; LDS transpose; 16B coalesced stores.
__global__ __launch_bounds__(256) void reduce1_k(const unsigned short* __restrict__ part,
                                                 const float* __restrict__ lam,
                                                 const float* __restrict__ tp,
                                                 unsigned short* __restrict__ Zt) {
  __shared__ unsigned short zt[64][72];
  const int t = threadIdx.x;
  const int r = t >> 2, q = t & 3;
  const int m = blockIdx.y * 64 + r;
  const int n0 = blockIdx.x * 128;
  const float tv = tp[0];
  const float s = sqrtf(fmaxf(lam[m], 0.f));
  const float cv = cosf(tv * s);
  const float pv = (s < 1e-5f) ? tv : (sinf(tv * s) / s);
  float acc[16];
#pragma unroll
  for (int i = 0; i < 16; ++i) acc[i] = 0.f;
  for (int ks = 0; ks < 8; ++ks) {
    const unsigned short* p = part + ((size_t)ks * N_NODES + m) * 512 + n0;
#pragma unroll
    for (int i = 0; i < 8; ++i) {
      ushort4 u = *(const ushort4*)&p[q * 4 + i * 16];  // (x_f, y_f, x_{f+1}, y_{f+1})
      acc[2 * i + 0] += cv * bf2f(u.x) + pv * bf2f(u.y);
      acc[2 * i + 1] += cv * bf2f(u.z) + pv * bf2f(u.w);
    }
  }
#pragma unroll
  for (int i = 0; i < 8; ++i) {
    int f = q * 2 + i * 8;
    zt[f + 0][r] = f2bf(acc[2 * i + 0]);
    zt[f + 1][r] = f2bf(acc[2 * i + 1]);
  }
  __syncthreads();
  const int f2 = t >> 2;
  const int gf = blockIdx.x * 64 + f2;
#pragma unroll
  for (int w = 0; w < 2; ++w) {
    int js = q * 8 + w * 32;
    ushort8v u = *(const ushort8v*)&zt[f2][js];
    *(ushort8v*)&Zt[(size_t)gf * N_NODES + blockIdx.y * 64 + js] = u;
  }
}

// --------------- reduce2: out[e] = sum_{ks<16} part[ks][e]  (bf16 partials -> f32)
__global__ __launch_bounds__(256) void reduce2_k(const unsigned short* __restrict__ part,
                                                 float* __restrict__ out) {
  const size_t e = ((size_t)blockIdx.x * 256 + threadIdx.x) * 4;
  float4 s = {0.f, 0.f, 0.f, 0.f};
#pragma unroll
  for (int ks = 0; ks < 16; ++ks) {
    ushort4 u = *(const ushort4*)&part[(size_t)ks * N_NODES * N_FEAT + e];
    s.x += bf2f(u.x); s.y += bf2f(u.y); s.z += bf2f(u.z); s.w += bf2f(u.w);
  }
  *(float4*)&out[e] = s;
}

extern "C" void kernel_launch(void* const* d_in, const int* in_sizes, int n_in,
                              void* d_out, int out_size, void* d_ws, size_t ws_size,
                              hipStream_t stream) {
  const float* x   = (const float*)d_in[0];
  const float* y   = (const float*)d_in[1];
  const float* tp  = (const float*)d_in[2];
  const float* lam = (const float*)d_in[3];
  const float* V   = (const float*)d_in[4];

  char* w = (char*)d_ws;
  unsigned short* Vbf  = (unsigned short*)w; w += (size_t)N_NODES * N_NODES * 2;
  unsigned short* Vtbf = (unsigned short*)w; w += (size_t)N_NODES * N_NODES * 2;
  unsigned short* S2T  = (unsigned short*)w; w += (size_t)512 * N_NODES * 2;
  unsigned short* Zt   = (unsigned short*)w; w += (size_t)N_FEAT * N_NODES * 2;
  unsigned short* partb = (unsigned short*)w; w += (size_t)8 * N_NODES * 512 * 2;  // 33.6MB bf16

  prep_all_k<<<4096 + 256, 256, 0, stream>>>(V, x, y, Vbf, Vtbf, S2T);
  // GEMM1: part[z][i][s] = Vt[i, z-chunk] . S2T[s, z-chunk]
  // z=8, Kc=512, BN=128 (4 ntiles, NTB=2); 1024 blocks; zz == xcd (4MB A-chunk per L2)
  gemm_swz<2><<<1024, 256, 0, stream>>>(Vtbf, S2T, partb, N_NODES, 512, 512,
                                        (size_t)N_NODES * 512);
  reduce1_k<<<dim3(512 / 128, N_NODES / 64), 256, 0, stream>>>(partb, lam, tp, Zt);
  // GEMM2: part[z][j][f] = Vbf[j, z-chunk] . Zt[f, z-chunk]
  // z=16, Kc=256, BN=128 (2 ntiles, NTB=1); 1024 blocks; each XCD covers 2 K-chunks
  gemm_swz<1><<<1024, 256, 0, stream>>>(Vbf, Zt, partb, N_NODES, 256, N_FEAT,
                                        (size_t)N_NODES * N_FEAT);
  reduce2_k<<<(N_NODES * N_FEAT) / 1024, 256, 0, stream>>>(partb, (float*)d_out);
}